// Round 1
// baseline (428.056 us; speedup 1.0000x reference)
//
#include <hip/hip_runtime.h>

// SAGE 2-layer GraphSAGE (mean aggr) on MI355X.
// Pipeline: CSR build (count/scan/fill) -> x->bf16 -> [agg -> fused GEMM] x2.
// GEMM: M=50000 x N=128 x K=256 (concat [agg|feat] along K), bf16 MFMA 16x16x32.

typedef __attribute__((ext_vector_type(8))) short short8;
typedef __attribute__((ext_vector_type(4))) float f32x4;

#define DEV __device__ __forceinline__

DEV unsigned short f2b(float f) {
  unsigned u = __builtin_bit_cast(unsigned, f);
  u += 0x7fffu + ((u >> 16) & 1u);   // round-to-nearest-even
  return (unsigned short)(u >> 16);
}
DEV float b2f(unsigned short h) {
  unsigned u = ((unsigned)h) << 16;
  return __builtin_bit_cast(float, u);
}

constexpr int N_NODES = 50000;
constexpr int N_EDGES = 800000;
constexpr int D = 128;

// ---------------- CSR build ----------------
__global__ void count_kernel(const int* __restrict__ dst, int* __restrict__ cnt) {
  int e = blockIdx.x * blockDim.x + threadIdx.x;
  if (e < N_EDGES) atomicAdd(&cnt[dst[e]], 1);
}

// Single-block chunked exclusive scan: each thread owns a contiguous segment.
__global__ void scan_kernel(const int* __restrict__ cnt, int* __restrict__ offs,
                            int* __restrict__ cursor) {
  __shared__ int tmp[1024];
  const int CH = (N_NODES + 1023) / 1024;  // 49
  int t = threadIdx.x;
  int beg = t * CH;
  int end = min(beg + CH, N_NODES);
  int sum = 0;
  for (int i = beg; i < end; ++i) sum += cnt[i];
  tmp[t] = sum;
  __syncthreads();
  for (int off = 1; off < 1024; off <<= 1) {
    int v = (t >= off) ? tmp[t - off] : 0;
    __syncthreads();
    tmp[t] += v;
    __syncthreads();
  }
  int run = tmp[t] - sum;  // exclusive prefix of this segment
  for (int i = beg; i < end; ++i) {
    offs[i] = run; cursor[i] = run; run += cnt[i];
  }
  if (t == 1023) offs[N_NODES] = tmp[1023];
}

__global__ void fill_kernel(const int* __restrict__ src, const int* __restrict__ dst,
                            int* __restrict__ cursor, int* __restrict__ csr_src) {
  int e = blockIdx.x * blockDim.x + threadIdx.x;
  if (e < N_EDGES) {
    int p = atomicAdd(&cursor[dst[e]], 1);
    csr_src[p] = src[e];
  }
}

// ---------------- fp32 -> bf16 convert ----------------
__global__ void convert_kernel(const float* __restrict__ in, unsigned short* __restrict__ out) {
  int i = blockIdx.x * blockDim.x + threadIdx.x;  // float4 index
  const int n4 = N_NODES * D / 4;
  if (i >= n4) return;
  f32x4 v = ((const f32x4*)in)[i];
  uint2 o;
  o.x = (unsigned)f2b(v.x) | ((unsigned)f2b(v.y) << 16);
  o.y = (unsigned)f2b(v.z) | ((unsigned)f2b(v.w) << 16);
  ((uint2*)out)[i] = o;
}

// ---------------- mean aggregation: one wave per node ----------------
// feat bf16 [N][128]; lane handles 2 columns (one dword). fp32 accumulate.
__global__ void agg_kernel(const unsigned short* __restrict__ feat,
                           const int* __restrict__ csr_src,
                           const int* __restrict__ offs,
                           unsigned short* __restrict__ out) {
  int w = (int)((blockIdx.x * blockDim.x + threadIdx.x) >> 6);
  int lane = threadIdx.x & 63;
  if (w >= N_NODES) return;
  int s = offs[w], e = offs[w + 1];
  const unsigned* f = (const unsigned*)feat;  // 64 dwords per row
  float ax = 0.f, ay = 0.f;
  int k = s;
  for (; k + 4 <= e; k += 4) {
    int s0 = csr_src[k], s1 = csr_src[k + 1], s2 = csr_src[k + 2], s3 = csr_src[k + 3];
    unsigned u0 = f[s0 * 64 + lane];
    unsigned u1 = f[s1 * 64 + lane];
    unsigned u2 = f[s2 * 64 + lane];
    unsigned u3 = f[s3 * 64 + lane];
    ax += b2f((unsigned short)u0) + b2f((unsigned short)u1) +
          b2f((unsigned short)u2) + b2f((unsigned short)u3);
    ay += b2f((unsigned short)(u0 >> 16)) + b2f((unsigned short)(u1 >> 16)) +
          b2f((unsigned short)(u2 >> 16)) + b2f((unsigned short)(u3 >> 16));
  }
  for (; k < e; ++k) {
    unsigned u = f[csr_src[k] * 64 + lane];
    ax += b2f((unsigned short)u);
    ay += b2f((unsigned short)(u >> 16));
  }
  float inv = 1.0f / (float)max(e - s, 1);
  unsigned o = (unsigned)f2b(ax * inv) | ((unsigned)f2b(ay * inv) << 16);
  ((unsigned*)out)[w * 64 + lane] = o;
}

// ---------------- fused SAGE GEMM ----------------
// out[i,:] = Aagg[i,:] @ Wl^T + Afeat[i,:] @ Wr^T + bias  (+optional ReLU)
// Block = 256 threads = 4 waves; wave computes 16 nodes x 128 cols.
// LDS holds [Wl|Wr] as bf16 in MFMA B-fragment order: Wlds[kchunk][n][8],
// kchunk = k/8 (0..15 for Wl, 16..31 for Wr). 32*128*8*2 = 64 KiB.
__global__ __launch_bounds__(256) void gemm_kernel(
    const unsigned short* __restrict__ Aagg,   // [N][128] bf16
    const unsigned short* __restrict__ Afeat,  // [N][128] bf16
    const float* __restrict__ Wl,              // [128][128] row-major [out][in]
    const float* __restrict__ Wr,
    const float* __restrict__ bias,            // [128]
    float* __restrict__ out_f32,               // used if relu_bf16 == 0
    unsigned short* __restrict__ out_bf16,     // used if relu_bf16 == 1
    int relu_bf16) {
  __shared__ unsigned short Wlds[32 * 128 * 8];

  // Stage weights fp32->bf16 into fragment order. 8192 float4s total.
  {
    const f32x4* wl4 = (const f32x4*)Wl;
    const f32x4* wr4 = (const f32x4*)Wr;
    for (int idx = threadIdx.x; idx < 8192; idx += 256) {
      int mat = idx >> 12;       // 0 = Wl, 1 = Wr
      int i = idx & 4095;        // float4 index within matrix
      int nrow = i >> 5;         // 32 float4 per 128-wide row
      int k = (i & 31) * 4;      // starting k of this float4
      f32x4 v = mat ? wr4[i] : wl4[i];
      int kchunk = (mat ? 16 : 0) + (k >> 3);
      int sub = k & 7;           // 0 or 4
      unsigned short* p = &Wlds[(kchunk * 128 + nrow) * 8 + sub];
      uint2 pk;
      pk.x = (unsigned)f2b(v.x) | ((unsigned)f2b(v.y) << 16);
      pk.y = (unsigned)f2b(v.z) | ((unsigned)f2b(v.w) << 16);
      *(uint2*)p = pk;
    }
  }
  __syncthreads();

  int wave = threadIdx.x >> 6;
  int lane = threadIdx.x & 63;
  int ml = lane & 15;     // A: m index / B: n index / C: col index
  int quad = lane >> 4;   // A,B: k-sub / C: row group
  int node0 = blockIdx.x * 64 + wave * 16;

  int arow = node0 + ml;
  if (arow >= N_NODES) arow = N_NODES - 1;  // clamp; stores guarded below

  f32x4 acc[8];
#pragma unroll
  for (int t = 0; t < 8; ++t) acc[t] = (f32x4){0.f, 0.f, 0.f, 0.f};

  const short8* lds8 = (const short8*)Wlds;  // frag idx = kchunk*128 + n
#pragma unroll
  for (int mat = 0; mat < 2; ++mat) {
    const unsigned short* A = mat ? Afeat : Aagg;
    const short8* arow8 = (const short8*)(A + (size_t)arow * D);  // 16 frags/row
    int kbase = mat * 16;
#pragma unroll
    for (int kc = 0; kc < 4; ++kc) {
      short8 af = arow8[kc * 4 + quad];          // A[m][kc*32 + quad*8 ..+8]
      int kchunk = kbase + kc * 4 + quad;
      const short8* brow = lds8 + kchunk * 128;
#pragma unroll
      for (int nt = 0; nt < 8; ++nt) {
        short8 bf = brow[nt * 16 + ml];          // W[n][k..k+8]
        acc[nt] = __builtin_amdgcn_mfma_f32_16x16x32_bf16(af, bf, acc[nt], 0, 0, 0);
      }
    }
  }

  // Epilogue: C/D layout col = lane&15, row = quad*4 + reg.
#pragma unroll
  for (int nt = 0; nt < 8; ++nt) {
    int col = nt * 16 + ml;
    float bv = bias[col];
#pragma unroll
    for (int r = 0; r < 4; ++r) {
      int node = node0 + quad * 4 + r;
      if (node >= N_NODES) continue;
      float v = acc[nt][r] + bv;
      if (relu_bf16) {
        v = v > 0.f ? v : 0.f;
        out_bf16[(size_t)node * D + col] = f2b(v);
      } else {
        out_f32[(size_t)node * D + col] = v;
      }
    }
  }
}

extern "C" void kernel_launch(void* const* d_in, const int* in_sizes, int n_in,
                              void* d_out, int out_size, void* d_ws, size_t ws_size,
                              hipStream_t stream) {
  const float* x   = (const float*)d_in[0];
  const int*   ei  = (const int*)d_in[1];   // [2][E] int32
  const float* Wl0 = (const float*)d_in[2];
  const float* bl0 = (const float*)d_in[3];
  const float* Wr0 = (const float*)d_in[4];
  const float* Wl1 = (const float*)d_in[5];
  const float* bl1 = (const float*)d_in[6];
  const float* Wr1 = (const float*)d_in[7];
  float* out = (float*)d_out;

  char* ws = (char*)d_ws;
  size_t o = 0;
  auto carve = [&](size_t bytes) {
    char* p = ws + o;
    o += bytes;
    o = (o + 255) & ~(size_t)255;
    return p;
  };
  int* cnt    = (int*)carve((size_t)N_NODES * 4);
  int* offs   = (int*)carve((size_t)(N_NODES + 1) * 4);
  int* cursor = (int*)carve((size_t)N_NODES * 4);
  int* csr    = (int*)carve((size_t)N_EDGES * 4);
  unsigned short* xb   = (unsigned short*)carve((size_t)N_NODES * D * 2);
  unsigned short* aggb = (unsigned short*)carve((size_t)N_NODES * D * 2);
  unsigned short* hb   = (unsigned short*)carve((size_t)N_NODES * D * 2);

  const int* srcp = ei;
  const int* dstp = ei + N_EDGES;

  hipMemsetAsync(cnt, 0, (size_t)N_NODES * 4, stream);
  count_kernel<<<(N_EDGES + 255) / 256, 256, 0, stream>>>(dstp, cnt);
  scan_kernel<<<1, 1024, 0, stream>>>(cnt, offs, cursor);
  fill_kernel<<<(N_EDGES + 255) / 256, 256, 0, stream>>>(srcp, dstp, cursor, csr);
  convert_kernel<<<(N_NODES * D / 4 + 255) / 256, 256, 0, stream>>>(x, xb);

  // Layer 0: agg(x) ; h = relu([agg|x] @ [Wl0|Wr0]^T + b0) -> bf16
  agg_kernel<<<(N_NODES + 3) / 4, 256, 0, stream>>>(xb, csr, offs, aggb);
  gemm_kernel<<<(N_NODES + 63) / 64, 256, 0, stream>>>(aggb, xb, Wl0, Wr0, bl0,
                                                       nullptr, hb, 1);
  // Layer 1: agg(h) ; out = [agg|h] @ [Wl1|Wr1]^T + b1 -> fp32
  agg_kernel<<<(N_NODES + 3) / 4, 256, 0, stream>>>(hb, csr, offs, aggb);
  gemm_kernel<<<(N_NODES + 63) / 64, 256, 0, stream>>>(aggb, hb, Wl1, Wr1, bl1,
                                                       out, nullptr, 0);
}

// Round 2
// 325.887 us; speedup vs baseline: 1.3135x; 1.3135x over previous
//
#include <hip/hip_runtime.h>

// SAGE 2-layer GraphSAGE (mean aggr) on MI355X.
// Pipeline: CSR build (count/3-phase scan/fill) -> x->bf16 -> [agg -> fused GEMM] x2.
// GEMM: M=50000 x N=128 x K=256 (concat [agg|feat] along K), bf16 MFMA 16x16x32.
// R1: replaced single-block scan (108us, latency-bound on 1 CU) with
//     hierarchical 3-kernel scan (partial-reduce / scan-bsums / final).

typedef __attribute__((ext_vector_type(8))) short short8;
typedef __attribute__((ext_vector_type(4))) float f32x4;

#define DEV __device__ __forceinline__

DEV unsigned short f2b(float f) {
  unsigned u = __builtin_bit_cast(unsigned, f);
  u += 0x7fffu + ((u >> 16) & 1u);   // round-to-nearest-even
  return (unsigned short)(u >> 16);
}
DEV float b2f(unsigned short h) {
  unsigned u = ((unsigned)h) << 16;
  return __builtin_bit_cast(float, u);
}

constexpr int N_NODES = 50000;
constexpr int N_EDGES = 800000;
constexpr int D = 128;
constexpr int N_SBLOCKS = (N_NODES + 255) / 256;  // 196

// ---------------- CSR build ----------------
__global__ void count_kernel(const int* __restrict__ dst, int* __restrict__ cnt) {
  int e = blockIdx.x * blockDim.x + threadIdx.x;
  if (e < N_EDGES) atomicAdd(&cnt[dst[e]], 1);
}

// Hierarchical scan, phase 1: per-block sums of cnt.
__global__ void scan_partial(const int* __restrict__ cnt, int* __restrict__ bsum) {
  __shared__ int tmp[256];
  int i = blockIdx.x * 256 + threadIdx.x;
  int t = threadIdx.x;
  tmp[t] = (i < N_NODES) ? cnt[i] : 0;
  __syncthreads();
  for (int off = 128; off > 0; off >>= 1) {
    if (t < off) tmp[t] += tmp[t + off];
    __syncthreads();
  }
  if (t == 0) bsum[blockIdx.x] = tmp[0];
}

// Phase 2: exclusive scan of the 196 block sums (single small block).
__global__ void scan_bsum(int* __restrict__ bsum) {
  __shared__ int tmp[256];
  int t = threadIdx.x;
  int v = (t < N_SBLOCKS) ? bsum[t] : 0;
  tmp[t] = v;
  __syncthreads();
  for (int off = 1; off < 256; off <<= 1) {
    int u = (t >= off) ? tmp[t - off] : 0;
    __syncthreads();
    tmp[t] += u;
    __syncthreads();
  }
  if (t < N_SBLOCKS) bsum[t] = tmp[t] - v;  // exclusive
}

// Phase 3: in-block exclusive scan + block prefix -> offs, cursor.
__global__ void scan_final(const int* __restrict__ cnt, const int* __restrict__ bsum,
                           int* __restrict__ offs, int* __restrict__ cursor) {
  __shared__ int tmp[256];
  int i = blockIdx.x * 256 + threadIdx.x;
  int t = threadIdx.x;
  int v = (i < N_NODES) ? cnt[i] : 0;
  tmp[t] = v;
  __syncthreads();
  for (int off = 1; off < 256; off <<= 1) {
    int u = (t >= off) ? tmp[t - off] : 0;
    __syncthreads();
    tmp[t] += u;
    __syncthreads();
  }
  int excl = tmp[t] - v + bsum[blockIdx.x];
  if (i < N_NODES) {
    offs[i] = excl;
    cursor[i] = excl;
    if (i == N_NODES - 1) offs[N_NODES] = excl + v;
  }
}

__global__ void fill_kernel(const int* __restrict__ src, const int* __restrict__ dst,
                            int* __restrict__ cursor, int* __restrict__ csr_src) {
  int e = blockIdx.x * blockDim.x + threadIdx.x;
  if (e < N_EDGES) {
    int p = atomicAdd(&cursor[dst[e]], 1);
    csr_src[p] = src[e];
  }
}

// ---------------- fp32 -> bf16 convert ----------------
__global__ void convert_kernel(const float* __restrict__ in, unsigned short* __restrict__ out) {
  int i = blockIdx.x * blockDim.x + threadIdx.x;  // float4 index
  const int n4 = N_NODES * D / 4;
  if (i >= n4) return;
  f32x4 v = ((const f32x4*)in)[i];
  uint2 o;
  o.x = (unsigned)f2b(v.x) | ((unsigned)f2b(v.y) << 16);
  o.y = (unsigned)f2b(v.z) | ((unsigned)f2b(v.w) << 16);
  ((uint2*)out)[i] = o;
}

// ---------------- mean aggregation: one wave per node ----------------
// feat bf16 [N][128]; lane handles 2 columns (one dword). fp32 accumulate.
__global__ void agg_kernel(const unsigned short* __restrict__ feat,
                           const int* __restrict__ csr_src,
                           const int* __restrict__ offs,
                           unsigned short* __restrict__ out) {
  int w = (int)((blockIdx.x * blockDim.x + threadIdx.x) >> 6);
  int lane = threadIdx.x & 63;
  if (w >= N_NODES) return;
  int s = offs[w], e = offs[w + 1];
  const unsigned* f = (const unsigned*)feat;  // 64 dwords per row
  float ax = 0.f, ay = 0.f;
  int k = s;
  for (; k + 4 <= e; k += 4) {
    int s0 = csr_src[k], s1 = csr_src[k + 1], s2 = csr_src[k + 2], s3 = csr_src[k + 3];
    unsigned u0 = f[s0 * 64 + lane];
    unsigned u1 = f[s1 * 64 + lane];
    unsigned u2 = f[s2 * 64 + lane];
    unsigned u3 = f[s3 * 64 + lane];
    ax += b2f((unsigned short)u0) + b2f((unsigned short)u1) +
          b2f((unsigned short)u2) + b2f((unsigned short)u3);
    ay += b2f((unsigned short)(u0 >> 16)) + b2f((unsigned short)(u1 >> 16)) +
          b2f((unsigned short)(u2 >> 16)) + b2f((unsigned short)(u3 >> 16));
  }
  for (; k < e; ++k) {
    unsigned u = f[csr_src[k] * 64 + lane];
    ax += b2f((unsigned short)u);
    ay += b2f((unsigned short)(u >> 16));
  }
  float inv = 1.0f / (float)max(e - s, 1);
  unsigned o = (unsigned)f2b(ax * inv) | ((unsigned)f2b(ay * inv) << 16);
  ((unsigned*)out)[w * 64 + lane] = o;
}

// ---------------- fused SAGE GEMM ----------------
// out[i,:] = Aagg[i,:] @ Wl^T + Afeat[i,:] @ Wr^T + bias  (+optional ReLU)
// Block = 256 threads = 4 waves; wave computes 16 nodes x 128 cols.
// LDS holds [Wl|Wr] as bf16 in MFMA B-fragment order: Wlds[kchunk][n][8],
// kchunk = k/8 (0..15 for Wl, 16..31 for Wr). 32*128*8*2 = 64 KiB.
__global__ __launch_bounds__(256) void gemm_kernel(
    const unsigned short* __restrict__ Aagg,   // [N][128] bf16
    const unsigned short* __restrict__ Afeat,  // [N][128] bf16
    const float* __restrict__ Wl,              // [128][128] row-major [out][in]
    const float* __restrict__ Wr,
    const float* __restrict__ bias,            // [128]
    float* __restrict__ out_f32,               // used if relu_bf16 == 0
    unsigned short* __restrict__ out_bf16,     // used if relu_bf16 == 1
    int relu_bf16) {
  __shared__ unsigned short Wlds[32 * 128 * 8];

  // Stage weights fp32->bf16 into fragment order. 8192 float4s total.
  {
    const f32x4* wl4 = (const f32x4*)Wl;
    const f32x4* wr4 = (const f32x4*)Wr;
    for (int idx = threadIdx.x; idx < 8192; idx += 256) {
      int mat = idx >> 12;       // 0 = Wl, 1 = Wr
      int i = idx & 4095;        // float4 index within matrix
      int nrow = i >> 5;         // 32 float4 per 128-wide row
      int k = (i & 31) * 4;      // starting k of this float4
      f32x4 v = mat ? wr4[i] : wl4[i];
      int kchunk = (mat ? 16 : 0) + (k >> 3);
      int sub = k & 7;           // 0 or 4
      unsigned short* p = &Wlds[(kchunk * 128 + nrow) * 8 + sub];
      uint2 pk;
      pk.x = (unsigned)f2b(v.x) | ((unsigned)f2b(v.y) << 16);
      pk.y = (unsigned)f2b(v.z) | ((unsigned)f2b(v.w) << 16);
      *(uint2*)p = pk;
    }
  }
  __syncthreads();

  int wave = threadIdx.x >> 6;
  int lane = threadIdx.x & 63;
  int ml = lane & 15;     // A: m index / B: n index / C: col index
  int quad = lane >> 4;   // A,B: k-sub / C: row group
  int node0 = blockIdx.x * 64 + wave * 16;

  int arow = node0 + ml;
  if (arow >= N_NODES) arow = N_NODES - 1;  // clamp; stores guarded below

  f32x4 acc[8];
#pragma unroll
  for (int t = 0; t < 8; ++t) acc[t] = (f32x4){0.f, 0.f, 0.f, 0.f};

  const short8* lds8 = (const short8*)Wlds;  // frag idx = kchunk*128 + n
#pragma unroll
  for (int mat = 0; mat < 2; ++mat) {
    const unsigned short* A = mat ? Afeat : Aagg;
    const short8* arow8 = (const short8*)(A + (size_t)arow * D);  // 16 frags/row
    int kbase = mat * 16;
#pragma unroll
    for (int kc = 0; kc < 4; ++kc) {
      short8 af = arow8[kc * 4 + quad];          // A[m][kc*32 + quad*8 ..+8]
      int kchunk = kbase + kc * 4 + quad;
      const short8* brow = lds8 + kchunk * 128;
#pragma unroll
      for (int nt = 0; nt < 8; ++nt) {
        short8 bf = brow[nt * 16 + ml];          // W[n][k..k+8]
        acc[nt] = __builtin_amdgcn_mfma_f32_16x16x32_bf16(af, bf, acc[nt], 0, 0, 0);
      }
    }
  }

  // Epilogue: C/D layout col = lane&15, row = quad*4 + reg.
#pragma unroll
  for (int nt = 0; nt < 8; ++nt) {
    int col = nt * 16 + ml;
    float bv = bias[col];
#pragma unroll
    for (int r = 0; r < 4; ++r) {
      int node = node0 + quad * 4 + r;
      if (node >= N_NODES) continue;
      float v = acc[nt][r] + bv;
      if (relu_bf16) {
        v = v > 0.f ? v : 0.f;
        out_bf16[(size_t)node * D + col] = f2b(v);
      } else {
        out_f32[(size_t)node * D + col] = v;
      }
    }
  }
}

extern "C" void kernel_launch(void* const* d_in, const int* in_sizes, int n_in,
                              void* d_out, int out_size, void* d_ws, size_t ws_size,
                              hipStream_t stream) {
  const float* x   = (const float*)d_in[0];
  const int*   ei  = (const int*)d_in[1];   // [2][E] int32
  const float* Wl0 = (const float*)d_in[2];
  const float* bl0 = (const float*)d_in[3];
  const float* Wr0 = (const float*)d_in[4];
  const float* Wl1 = (const float*)d_in[5];
  const float* bl1 = (const float*)d_in[6];
  const float* Wr1 = (const float*)d_in[7];
  float* out = (float*)d_out;

  char* ws = (char*)d_ws;
  size_t o = 0;
  auto carve = [&](size_t bytes) {
    char* p = ws + o;
    o += bytes;
    o = (o + 255) & ~(size_t)255;
    return p;
  };
  int* cnt    = (int*)carve((size_t)N_NODES * 4);
  int* offs   = (int*)carve((size_t)(N_NODES + 1) * 4);
  int* cursor = (int*)carve((size_t)N_NODES * 4);
  int* csr    = (int*)carve((size_t)N_EDGES * 4);
  int* bsum   = (int*)carve((size_t)N_SBLOCKS * 4);
  unsigned short* xb   = (unsigned short*)carve((size_t)N_NODES * D * 2);
  unsigned short* aggb = (unsigned short*)carve((size_t)N_NODES * D * 2);
  unsigned short* hb   = (unsigned short*)carve((size_t)N_NODES * D * 2);

  const int* srcp = ei;
  const int* dstp = ei + N_EDGES;

  hipMemsetAsync(cnt, 0, (size_t)N_NODES * 4, stream);
  count_kernel<<<(N_EDGES + 255) / 256, 256, 0, stream>>>(dstp, cnt);
  scan_partial<<<N_SBLOCKS, 256, 0, stream>>>(cnt, bsum);
  scan_bsum<<<1, 256, 0, stream>>>(bsum);
  scan_final<<<N_SBLOCKS, 256, 0, stream>>>(cnt, bsum, offs, cursor);
  fill_kernel<<<(N_EDGES + 255) / 256, 256, 0, stream>>>(srcp, dstp, cursor, csr);
  convert_kernel<<<(N_NODES * D / 4 + 255) / 256, 256, 0, stream>>>(x, xb);

  // Layer 0: agg(x) ; h = relu([agg|x] @ [Wl0|Wr0]^T + b0) -> bf16
  agg_kernel<<<(N_NODES + 3) / 4, 256, 0, stream>>>(xb, csr, offs, aggb);
  gemm_kernel<<<(N_NODES + 63) / 64, 256, 0, stream>>>(aggb, xb, Wl0, Wr0, bl0,
                                                       nullptr, hb, 1);
  // Layer 1: agg(h) ; out = [agg|h] @ [Wl1|Wr1]^T + b1 -> fp32
  agg_kernel<<<(N_NODES + 3) / 4, 256, 0, stream>>>(hb, csr, offs, aggb);
  gemm_kernel<<<(N_NODES + 63) / 64, 256, 0, stream>>>(aggb, hb, Wl1, Wr1, bl1,
                                                       out, nullptr, 0);
}

// Round 3
// 263.109 us; speedup vs baseline: 1.6269x; 1.2386x over previous
//
#include <hip/hip_runtime.h>

// SAGE 2-layer GraphSAGE (mean aggr) on MI355X.
// Pipeline: bucketed CSR build (bin/scan/fill2) -> x->bf16 -> [agg -> fused GEMM] x2.
// GEMM: M=50000 x N=128 x K=256 (concat [agg|feat] along K), bf16 MFMA 16x16x32.
// R1: hierarchical scan (scan was 108us on 1 CU).
// R2: fill_kernel had 52MB WRITE_SIZE for 3.2MB of CSR (cross-XCD partial-line
//     writeback amplification of the random scatter). Replaced count/scan/fill
//     with bucket-local build: bin (chunked, near-dense writes) + per-bucket
//     fill (scatter confined to 16KB span on one XCD).

typedef __attribute__((ext_vector_type(8))) short short8;
typedef __attribute__((ext_vector_type(4))) float f32x4;

#define DEV __device__ __forceinline__

DEV unsigned short f2b(float f) {
  unsigned u = __builtin_bit_cast(unsigned, f);
  u += 0x7fffu + ((u >> 16) & 1u);   // round-to-nearest-even
  return (unsigned short)(u >> 16);
}
DEV float b2f(unsigned short h) {
  unsigned u = ((unsigned)h) << 16;
  return __builtin_bit_cast(float, u);
}

constexpr int N_NODES = 50000;
constexpr int N_EDGES = 800000;
constexpr int D = 128;
constexpr int NBUCK = (N_NODES + 255) / 256;          // 196 buckets of 256 nodes
constexpr int BCAP = 5120;                            // mean 4096, +16 sigma
constexpr int EPB = (N_EDGES + NBUCK - 1) / NBUCK;    // edges per bin block

// ---------------- bucketed CSR build ----------------
// Phase A: bin edges into NBUCK buckets, packed (dloc<<16)|src (src<2^16).
__global__ __launch_bounds__(256) void bin_kernel(const int* __restrict__ src,
                                                  const int* __restrict__ dst,
                                                  int* __restrict__ g_bcnt,
                                                  unsigned* __restrict__ staging) {
  __shared__ int cnt[NBUCK];
  __shared__ int cur[NBUCK];
  int t = threadIdx.x;
  for (int i = t; i < NBUCK; i += 256) cnt[i] = 0;
  __syncthreads();
  int beg = blockIdx.x * EPB;
  int end = min(beg + EPB, N_EDGES);
  for (int e = beg + t; e < end; e += 256) {
    atomicAdd(&cnt[dst[e] >> 8], 1);
  }
  __syncthreads();
  for (int i = t; i < NBUCK; i += 256) {
    cur[i] = atomicAdd(&g_bcnt[i], cnt[i]);   // contiguous chunk base
  }
  __syncthreads();
  for (int e = beg + t; e < end; e += 256) {
    int d = dst[e];
    int b = d >> 8;
    int p = atomicAdd(&cur[b], 1);
    if (p >= BCAP) p = BCAP - 1;  // paranoia; statistically unreachable
    staging[b * BCAP + p] = ((unsigned)(d & 255) << 16) | (unsigned)src[e];
  }
}

// Phase B1: exclusive scan of bucket counts.
__global__ void scan_buck(const int* __restrict__ g_bcnt, int* __restrict__ g_bbase,
                          int* __restrict__ offs) {
  __shared__ int tmp[256];
  int t = threadIdx.x;
  int v = (t < NBUCK) ? g_bcnt[t] : 0;
  tmp[t] = v;
  __syncthreads();
  for (int off = 1; off < 256; off <<= 1) {
    int u = (t >= off) ? tmp[t - off] : 0;
    __syncthreads();
    tmp[t] += u;
    __syncthreads();
  }
  if (t < NBUCK) g_bbase[t] = tmp[t] - v;
  if (t == 0) offs[N_NODES] = N_EDGES;
}

// Phase B2: one block per bucket. LDS histogram+scan over the 256 node slots,
// write offs (coalesced), scatter src into this bucket's contiguous CSR span.
__global__ __launch_bounds__(256) void fill2_kernel(const unsigned* __restrict__ staging,
                                                    const int* __restrict__ g_bcnt,
                                                    const int* __restrict__ g_bbase,
                                                    int* __restrict__ offs,
                                                    int* __restrict__ csr) {
  __shared__ int hist[256];
  __shared__ int tmp[256];
  __shared__ int cur[256];
  int b = blockIdx.x;
  int t = threadIdx.x;
  int n = g_bcnt[b];
  int bb = g_bbase[b];
  const unsigned* st = staging + b * BCAP;
  hist[t] = 0;
  __syncthreads();
  for (int e = t; e < n; e += 256) atomicAdd(&hist[st[e] >> 16], 1);
  __syncthreads();
  int v = hist[t];
  tmp[t] = v;
  __syncthreads();
  for (int off = 1; off < 256; off <<= 1) {
    int u = (t >= off) ? tmp[t - off] : 0;
    __syncthreads();
    tmp[t] += u;
    __syncthreads();
  }
  int excl = tmp[t] - v;
  int node = b * 256 + t;
  if (node < N_NODES) offs[node] = bb + excl;
  cur[t] = bb + excl;
  __syncthreads();
  for (int e = t; e < n; e += 256) {
    unsigned pk = st[e];
    int p = atomicAdd(&cur[pk >> 16], 1);
    csr[p] = (int)(pk & 0xffffu);
  }
}

// ---------------- fp32 -> bf16 convert ----------------
__global__ void convert_kernel(const float* __restrict__ in, unsigned short* __restrict__ out) {
  int i = blockIdx.x * blockDim.x + threadIdx.x;  // float4 index
  const int n4 = N_NODES * D / 4;
  if (i >= n4) return;
  f32x4 v = ((const f32x4*)in)[i];
  uint2 o;
  o.x = (unsigned)f2b(v.x) | ((unsigned)f2b(v.y) << 16);
  o.y = (unsigned)f2b(v.z) | ((unsigned)f2b(v.w) << 16);
  ((uint2*)out)[i] = o;
}

// ---------------- mean aggregation: one wave per node ----------------
__global__ void agg_kernel(const unsigned short* __restrict__ feat,
                           const int* __restrict__ csr_src,
                           const int* __restrict__ offs,
                           unsigned short* __restrict__ out) {
  int w = (int)((blockIdx.x * blockDim.x + threadIdx.x) >> 6);
  int lane = threadIdx.x & 63;
  if (w >= N_NODES) return;
  int s = offs[w], e = offs[w + 1];
  const unsigned* f = (const unsigned*)feat;  // 64 dwords per row
  float ax = 0.f, ay = 0.f;
  int k = s;
  for (; k + 4 <= e; k += 4) {
    int s0 = csr_src[k], s1 = csr_src[k + 1], s2 = csr_src[k + 2], s3 = csr_src[k + 3];
    unsigned u0 = f[s0 * 64 + lane];
    unsigned u1 = f[s1 * 64 + lane];
    unsigned u2 = f[s2 * 64 + lane];
    unsigned u3 = f[s3 * 64 + lane];
    ax += b2f((unsigned short)u0) + b2f((unsigned short)u1) +
          b2f((unsigned short)u2) + b2f((unsigned short)u3);
    ay += b2f((unsigned short)(u0 >> 16)) + b2f((unsigned short)(u1 >> 16)) +
          b2f((unsigned short)(u2 >> 16)) + b2f((unsigned short)(u3 >> 16));
  }
  for (; k < e; ++k) {
    unsigned u = f[csr_src[k] * 64 + lane];
    ax += b2f((unsigned short)u);
    ay += b2f((unsigned short)(u >> 16));
  }
  float inv = 1.0f / (float)max(e - s, 1);
  unsigned o = (unsigned)f2b(ax * inv) | ((unsigned)f2b(ay * inv) << 16);
  ((unsigned*)out)[w * 64 + lane] = o;
}

// ---------------- fused SAGE GEMM ----------------
__global__ __launch_bounds__(256) void gemm_kernel(
    const unsigned short* __restrict__ Aagg,   // [N][128] bf16
    const unsigned short* __restrict__ Afeat,  // [N][128] bf16
    const float* __restrict__ Wl,              // [128][128] row-major [out][in]
    const float* __restrict__ Wr,
    const float* __restrict__ bias,            // [128]
    float* __restrict__ out_f32,               // used if relu_bf16 == 0
    unsigned short* __restrict__ out_bf16,     // used if relu_bf16 == 1
    int relu_bf16) {
  __shared__ unsigned short Wlds[32 * 128 * 8];

  {
    const f32x4* wl4 = (const f32x4*)Wl;
    const f32x4* wr4 = (const f32x4*)Wr;
    for (int idx = threadIdx.x; idx < 8192; idx += 256) {
      int mat = idx >> 12;
      int i = idx & 4095;
      int nrow = i >> 5;
      int k = (i & 31) * 4;
      f32x4 v = mat ? wr4[i] : wl4[i];
      int kchunk = (mat ? 16 : 0) + (k >> 3);
      int sub = k & 7;
      unsigned short* p = &Wlds[(kchunk * 128 + nrow) * 8 + sub];
      uint2 pk;
      pk.x = (unsigned)f2b(v.x) | ((unsigned)f2b(v.y) << 16);
      pk.y = (unsigned)f2b(v.z) | ((unsigned)f2b(v.w) << 16);
      *(uint2*)p = pk;
    }
  }
  __syncthreads();

  int wave = threadIdx.x >> 6;
  int lane = threadIdx.x & 63;
  int ml = lane & 15;
  int quad = lane >> 4;
  int node0 = blockIdx.x * 64 + wave * 16;

  int arow = node0 + ml;
  if (arow >= N_NODES) arow = N_NODES - 1;

  f32x4 acc[8];
#pragma unroll
  for (int t = 0; t < 8; ++t) acc[t] = (f32x4){0.f, 0.f, 0.f, 0.f};

  const short8* lds8 = (const short8*)Wlds;
#pragma unroll
  for (int mat = 0; mat < 2; ++mat) {
    const unsigned short* A = mat ? Afeat : Aagg;
    const short8* arow8 = (const short8*)(A + (size_t)arow * D);
    int kbase = mat * 16;
#pragma unroll
    for (int kc = 0; kc < 4; ++kc) {
      short8 af = arow8[kc * 4 + quad];
      int kchunk = kbase + kc * 4 + quad;
      const short8* brow = lds8 + kchunk * 128;
#pragma unroll
      for (int nt = 0; nt < 8; ++nt) {
        short8 bf = brow[nt * 16 + ml];
        acc[nt] = __builtin_amdgcn_mfma_f32_16x16x32_bf16(af, bf, acc[nt], 0, 0, 0);
      }
    }
  }

#pragma unroll
  for (int nt = 0; nt < 8; ++nt) {
    int col = nt * 16 + ml;
    float bv = bias[col];
#pragma unroll
    for (int r = 0; r < 4; ++r) {
      int node = node0 + quad * 4 + r;
      if (node >= N_NODES) continue;
      float v = acc[nt][r] + bv;
      if (relu_bf16) {
        v = v > 0.f ? v : 0.f;
        out_bf16[(size_t)node * D + col] = f2b(v);
      } else {
        out_f32[(size_t)node * D + col] = v;
      }
    }
  }
}

extern "C" void kernel_launch(void* const* d_in, const int* in_sizes, int n_in,
                              void* d_out, int out_size, void* d_ws, size_t ws_size,
                              hipStream_t stream) {
  const float* x   = (const float*)d_in[0];
  const int*   ei  = (const int*)d_in[1];   // [2][E] int32
  const float* Wl0 = (const float*)d_in[2];
  const float* bl0 = (const float*)d_in[3];
  const float* Wr0 = (const float*)d_in[4];
  const float* Wl1 = (const float*)d_in[5];
  const float* bl1 = (const float*)d_in[6];
  const float* Wr1 = (const float*)d_in[7];
  float* out = (float*)d_out;

  char* ws = (char*)d_ws;
  size_t o = 0;
  auto carve = [&](size_t bytes) {
    char* p = ws + o;
    o += bytes;
    o = (o + 255) & ~(size_t)255;
    return p;
  };
  int* offs       = (int*)carve((size_t)(N_NODES + 1) * 4);
  int* csr        = (int*)carve((size_t)N_EDGES * 4);
  int* g_bcnt     = (int*)carve((size_t)NBUCK * 4);
  int* g_bbase    = (int*)carve((size_t)NBUCK * 4);
  unsigned* staging = (unsigned*)carve((size_t)NBUCK * BCAP * 4);
  unsigned short* xb   = (unsigned short*)carve((size_t)N_NODES * D * 2);
  unsigned short* aggb = (unsigned short*)carve((size_t)N_NODES * D * 2);
  unsigned short* hb   = (unsigned short*)carve((size_t)N_NODES * D * 2);

  const int* srcp = ei;
  const int* dstp = ei + N_EDGES;

  hipMemsetAsync(g_bcnt, 0, (size_t)NBUCK * 4, stream);
  bin_kernel<<<NBUCK, 256, 0, stream>>>(srcp, dstp, g_bcnt, staging);
  scan_buck<<<1, 256, 0, stream>>>(g_bcnt, g_bbase, offs);
  fill2_kernel<<<NBUCK, 256, 0, stream>>>(staging, g_bcnt, g_bbase, offs, csr);
  convert_kernel<<<(N_NODES * D / 4 + 255) / 256, 256, 0, stream>>>(x, xb);

  // Layer 0: agg(x) ; h = relu([agg|x] @ [Wl0|Wr0]^T + b0) -> bf16
  agg_kernel<<<(N_NODES + 3) / 4, 256, 0, stream>>>(xb, csr, offs, aggb);
  gemm_kernel<<<(N_NODES + 63) / 64, 256, 0, stream>>>(aggb, xb, Wl0, Wr0, bl0,
                                                       nullptr, hb, 1);
  // Layer 1: agg(h) ; out = [agg|h] @ [Wl1|Wr1]^T + b1 -> fp32
  agg_kernel<<<(N_NODES + 3) / 4, 256, 0, stream>>>(hb, csr, offs, aggb);
  gemm_kernel<<<(N_NODES + 63) / 64, 256, 0, stream>>>(aggb, hb, Wl1, Wr1, bl1,
                                                       out, nullptr, 0);
}

// Round 4
// 235.902 us; speedup vs baseline: 1.8146x; 1.1153x over previous
//
#include <hip/hip_runtime.h>

// SAGE 2-layer GraphSAGE (mean aggr) on MI355X.
// Pipeline: bucketed CSR build (bin/scan/fill2) -> x->bf16 + weight prep ->
//           [agg -> LDS-free MFMA GEMM] x2.
// R1: hierarchical scan (single-block scan was 108us on 1 CU).
// R2: bucket-local CSR build (random scatter had 16x write amplification).
// R3: GEMM was 42.8us: 2.8M LDS bank conflicts (16B-stride frag reads = 8-way),
//     2 blocks/CU (64KB LDS), per-block weight re-staging. Replaced with
//     LDS-free GEMM reading pre-formatted bf16 B-fragments from global (L2-hot,
//     64KB), prepared once by prep_weights.

typedef __attribute__((ext_vector_type(8))) short short8;
typedef __attribute__((ext_vector_type(4))) float f32x4;

#define DEV __device__ __forceinline__

DEV unsigned short f2b(float f) {
  unsigned u = __builtin_bit_cast(unsigned, f);
  u += 0x7fffu + ((u >> 16) & 1u);   // round-to-nearest-even
  return (unsigned short)(u >> 16);
}
DEV float b2f(unsigned short h) {
  unsigned u = ((unsigned)h) << 16;
  return __builtin_bit_cast(float, u);
}

constexpr int N_NODES = 50000;
constexpr int N_EDGES = 800000;
constexpr int D = 128;
constexpr int NBUCK = (N_NODES + 255) / 256;          // 196 buckets of 256 nodes
constexpr int BCAP = 5120;                            // mean 4096, +16 sigma
constexpr int EPB = (N_EDGES + NBUCK - 1) / NBUCK;    // edges per bin block

// ---------------- bucketed CSR build ----------------
__global__ __launch_bounds__(256) void bin_kernel(const int* __restrict__ src,
                                                  const int* __restrict__ dst,
                                                  int* __restrict__ g_bcnt,
                                                  unsigned* __restrict__ staging) {
  __shared__ int cnt[NBUCK];
  __shared__ int cur[NBUCK];
  int t = threadIdx.x;
  for (int i = t; i < NBUCK; i += 256) cnt[i] = 0;
  __syncthreads();
  int beg = blockIdx.x * EPB;
  int end = min(beg + EPB, N_EDGES);
  for (int e = beg + t; e < end; e += 256) {
    atomicAdd(&cnt[dst[e] >> 8], 1);
  }
  __syncthreads();
  for (int i = t; i < NBUCK; i += 256) {
    cur[i] = atomicAdd(&g_bcnt[i], cnt[i]);   // contiguous chunk base
  }
  __syncthreads();
  for (int e = beg + t; e < end; e += 256) {
    int d = dst[e];
    int b = d >> 8;
    int p = atomicAdd(&cur[b], 1);
    if (p >= BCAP) p = BCAP - 1;  // paranoia; statistically unreachable
    staging[b * BCAP + p] = ((unsigned)(d & 255) << 16) | (unsigned)src[e];
  }
}

__global__ void scan_buck(const int* __restrict__ g_bcnt, int* __restrict__ g_bbase,
                          int* __restrict__ offs) {
  __shared__ int tmp[256];
  int t = threadIdx.x;
  int v = (t < NBUCK) ? g_bcnt[t] : 0;
  tmp[t] = v;
  __syncthreads();
  for (int off = 1; off < 256; off <<= 1) {
    int u = (t >= off) ? tmp[t - off] : 0;
    __syncthreads();
    tmp[t] += u;
    __syncthreads();
  }
  if (t < NBUCK) g_bbase[t] = tmp[t] - v;
  if (t == 0) offs[N_NODES] = N_EDGES;
}

__global__ __launch_bounds__(256) void fill2_kernel(const unsigned* __restrict__ staging,
                                                    const int* __restrict__ g_bcnt,
                                                    const int* __restrict__ g_bbase,
                                                    int* __restrict__ offs,
                                                    int* __restrict__ csr) {
  __shared__ int hist[256];
  __shared__ int tmp[256];
  __shared__ int cur[256];
  int b = blockIdx.x;
  int t = threadIdx.x;
  int n = g_bcnt[b];
  int bb = g_bbase[b];
  const unsigned* st = staging + b * BCAP;
  hist[t] = 0;
  __syncthreads();
  for (int e = t; e < n; e += 256) atomicAdd(&hist[st[e] >> 16], 1);
  __syncthreads();
  int v = hist[t];
  tmp[t] = v;
  __syncthreads();
  for (int off = 1; off < 256; off <<= 1) {
    int u = (t >= off) ? tmp[t - off] : 0;
    __syncthreads();
    tmp[t] += u;
    __syncthreads();
  }
  int excl = tmp[t] - v;
  int node = b * 256 + t;
  if (node < N_NODES) offs[node] = bb + excl;
  cur[t] = bb + excl;
  __syncthreads();
  for (int e = t; e < n; e += 256) {
    unsigned pk = st[e];
    int p = atomicAdd(&cur[pk >> 16], 1);
    csr[p] = (int)(pk & 0xffffu);
  }
}

// ---------------- fp32 -> bf16 convert ----------------
__global__ void convert_kernel(const float* __restrict__ in, unsigned short* __restrict__ out) {
  int i = blockIdx.x * blockDim.x + threadIdx.x;  // float4 index
  const int n4 = N_NODES * D / 4;
  if (i >= n4) return;
  f32x4 v = ((const f32x4*)in)[i];
  uint2 o;
  o.x = (unsigned)f2b(v.x) | ((unsigned)f2b(v.y) << 16);
  o.y = (unsigned)f2b(v.z) | ((unsigned)f2b(v.w) << 16);
  ((uint2*)out)[i] = o;
}

// ---------------- weight prep: fp32 [out][in] -> bf16 B-fragment order ----
// Bf layout per layer: frag f = kchunk*128 + n (kchunk 0..31: 0-15 Wl k=8*kc,
// 16-31 Wr), 8 bf16 elements W[n][k..k+8]. 64KB per layer.
__global__ void prep_weights(const float* __restrict__ Wl0, const float* __restrict__ Wr0,
                             const float* __restrict__ Wl1, const float* __restrict__ Wr1,
                             unsigned short* __restrict__ Bf) {
  int f = blockIdx.x * blockDim.x + threadIdx.x;  // 0 .. 2*32*128-1
  if (f >= 2 * 32 * 128) return;
  int layer = f >> 12;
  int kchunk = (f >> 7) & 31;
  int n = f & 127;
  const float* W;
  if (layer == 0) W = (kchunk < 16) ? Wl0 : Wr0;
  else            W = (kchunk < 16) ? Wl1 : Wr1;
  int k = (kchunk & 15) * 8;
  const f32x4* row = (const f32x4*)(W + n * D + k);
  f32x4 a = row[0], b = row[1];
  uint2 lo, hi;
  lo.x = (unsigned)f2b(a.x) | ((unsigned)f2b(a.y) << 16);
  lo.y = (unsigned)f2b(a.z) | ((unsigned)f2b(a.w) << 16);
  hi.x = (unsigned)f2b(b.x) | ((unsigned)f2b(b.y) << 16);
  hi.y = (unsigned)f2b(b.z) | ((unsigned)f2b(b.w) << 16);
  uint4 pk = {lo.x, lo.y, hi.x, hi.y};
  *(uint4*)(Bf + (size_t)f * 8) = pk;
}

// ---------------- mean aggregation: one wave per node ----------------
__global__ void agg_kernel(const unsigned short* __restrict__ feat,
                           const int* __restrict__ csr_src,
                           const int* __restrict__ offs,
                           unsigned short* __restrict__ out) {
  int w = (int)((blockIdx.x * blockDim.x + threadIdx.x) >> 6);
  int lane = threadIdx.x & 63;
  if (w >= N_NODES) return;
  int s = offs[w], e = offs[w + 1];
  const unsigned* f = (const unsigned*)feat;  // 64 dwords per row
  float ax = 0.f, ay = 0.f;
  int k = s;
  for (; k + 4 <= e; k += 4) {
    int s0 = csr_src[k], s1 = csr_src[k + 1], s2 = csr_src[k + 2], s3 = csr_src[k + 3];
    unsigned u0 = f[s0 * 64 + lane];
    unsigned u1 = f[s1 * 64 + lane];
    unsigned u2 = f[s2 * 64 + lane];
    unsigned u3 = f[s3 * 64 + lane];
    ax += b2f((unsigned short)u0) + b2f((unsigned short)u1) +
          b2f((unsigned short)u2) + b2f((unsigned short)u3);
    ay += b2f((unsigned short)(u0 >> 16)) + b2f((unsigned short)(u1 >> 16)) +
          b2f((unsigned short)(u2 >> 16)) + b2f((unsigned short)(u3 >> 16));
  }
  for (; k < e; ++k) {
    unsigned u = f[csr_src[k] * 64 + lane];
    ax += b2f((unsigned short)u);
    ay += b2f((unsigned short)(u >> 16));
  }
  float inv = 1.0f / (float)max(e - s, 1);
  unsigned o = (unsigned)f2b(ax * inv) | ((unsigned)f2b(ay * inv) << 16);
  ((unsigned*)out)[w * 64 + lane] = o;
}

// ---------------- LDS-free fused SAGE GEMM ----------------
// out[i,:] = Aagg[i,:] @ Wl^T + Afeat[i,:] @ Wr^T + bias  (+optional ReLU)
// Wave computes 16 nodes x 128 cols. B-frags streamed from global (L2-hot).
__global__ __launch_bounds__(256) void gemm_kernel(
    const unsigned short* __restrict__ Aagg,   // [N][128] bf16
    const unsigned short* __restrict__ Afeat,  // [N][128] bf16
    const unsigned short* __restrict__ Bf,     // frag-ordered weights, this layer
    const float* __restrict__ bias,            // [128]
    float* __restrict__ out_f32,               // used if relu_bf16 == 0
    unsigned short* __restrict__ out_bf16,     // used if relu_bf16 == 1
    int relu_bf16) {
  int wave = threadIdx.x >> 6;
  int lane = threadIdx.x & 63;
  int ml = lane & 15;     // A: m / B: n / C: col
  int quad = lane >> 4;   // A,B: k-sub / C: row group
  int node0 = blockIdx.x * 64 + wave * 16;

  int arow = node0 + ml;
  if (arow >= N_NODES) arow = N_NODES - 1;  // clamp; stores guarded below

  f32x4 acc[8];
#pragma unroll
  for (int t = 0; t < 8; ++t) acc[t] = (f32x4){0.f, 0.f, 0.f, 0.f};

  const short8* bf8 = (const short8*)Bf;  // frag idx = kchunk*128 + n
#pragma unroll
  for (int mat = 0; mat < 2; ++mat) {
    const unsigned short* A = mat ? Afeat : Aagg;
    const short8* arow8 = (const short8*)(A + (size_t)arow * D);  // 16 frags/row
    int kbase = mat * 16;
#pragma unroll
    for (int kc = 0; kc < 4; ++kc) {
      short8 af = arow8[kc * 4 + quad];          // A[m][kc*32 + quad*8 ..+8]
      int kchunk = kbase + kc * 4 + quad;
      const short8* brow = bf8 + kchunk * 128;
#pragma unroll
      for (int nt = 0; nt < 8; ++nt) {
        short8 bfr = brow[nt * 16 + ml];         // W[n][k..k+8]
        acc[nt] = __builtin_amdgcn_mfma_f32_16x16x32_bf16(af, bfr, acc[nt], 0, 0, 0);
      }
    }
  }

  // Epilogue: C/D layout col = lane&15, row = quad*4 + reg.
#pragma unroll
  for (int nt = 0; nt < 8; ++nt) {
    int col = nt * 16 + ml;
    float bv = bias[col];
#pragma unroll
    for (int r = 0; r < 4; ++r) {
      int node = node0 + quad * 4 + r;
      if (node >= N_NODES) continue;
      float v = acc[nt][r] + bv;
      if (relu_bf16) {
        v = v > 0.f ? v : 0.f;
        out_bf16[(size_t)node * D + col] = f2b(v);
      } else {
        out_f32[(size_t)node * D + col] = v;
      }
    }
  }
}

extern "C" void kernel_launch(void* const* d_in, const int* in_sizes, int n_in,
                              void* d_out, int out_size, void* d_ws, size_t ws_size,
                              hipStream_t stream) {
  const float* x   = (const float*)d_in[0];
  const int*   ei  = (const int*)d_in[1];   // [2][E] int32
  const float* Wl0 = (const float*)d_in[2];
  const float* bl0 = (const float*)d_in[3];
  const float* Wr0 = (const float*)d_in[4];
  const float* Wl1 = (const float*)d_in[5];
  const float* bl1 = (const float*)d_in[6];
  const float* Wr1 = (const float*)d_in[7];
  float* out = (float*)d_out;

  char* ws = (char*)d_ws;
  size_t o = 0;
  auto carve = [&](size_t bytes) {
    char* p = ws + o;
    o += bytes;
    o = (o + 255) & ~(size_t)255;
    return p;
  };
  int* offs       = (int*)carve((size_t)(N_NODES + 1) * 4);
  int* csr        = (int*)carve((size_t)N_EDGES * 4);
  int* g_bcnt     = (int*)carve((size_t)NBUCK * 4);
  int* g_bbase    = (int*)carve((size_t)NBUCK * 4);
  unsigned* staging = (unsigned*)carve((size_t)NBUCK * BCAP * 4);
  unsigned short* Bf   = (unsigned short*)carve((size_t)2 * 32 * 128 * 8 * 2);
  unsigned short* xb   = (unsigned short*)carve((size_t)N_NODES * D * 2);
  unsigned short* aggb = (unsigned short*)carve((size_t)N_NODES * D * 2);
  unsigned short* hb   = (unsigned short*)carve((size_t)N_NODES * D * 2);

  const int* srcp = ei;
  const int* dstp = ei + N_EDGES;

  hipMemsetAsync(g_bcnt, 0, (size_t)NBUCK * 4, stream);
  bin_kernel<<<NBUCK, 256, 0, stream>>>(srcp, dstp, g_bcnt, staging);
  scan_buck<<<1, 256, 0, stream>>>(g_bcnt, g_bbase, offs);
  fill2_kernel<<<NBUCK, 256, 0, stream>>>(staging, g_bcnt, g_bbase, offs, csr);
  convert_kernel<<<(N_NODES * D / 4 + 255) / 256, 256, 0, stream>>>(x, xb);
  prep_weights<<<(2 * 32 * 128 + 255) / 256, 256, 0, stream>>>(Wl0, Wr0, Wl1, Wr1, Bf);

  const int GEMM_BLOCKS = (N_NODES + 63) / 64;
  // Layer 0: agg(x) ; h = relu([agg|x] @ [Wl0|Wr0]^T + b0) -> bf16
  agg_kernel<<<(N_NODES + 3) / 4, 256, 0, stream>>>(xb, csr, offs, aggb);
  gemm_kernel<<<GEMM_BLOCKS, 256, 0, stream>>>(aggb, xb, Bf, bl0, nullptr, hb, 1);
  // Layer 1: agg(h) ; out = [agg|h] @ [Wl1|Wr1]^T + b1 -> fp32
  agg_kernel<<<(N_NODES + 3) / 4, 256, 0, stream>>>(hb, csr, offs, aggb);
  gemm_kernel<<<GEMM_BLOCKS, 256, 0, stream>>>(aggb, hb, Bf + 32 * 128 * 8, bl1,
                                               out, nullptr, 0);
}